// Round 14
// baseline (200.223 us; speedup 1.0000x reference)
//
#include <hip/hip_runtime.h>
#include <math.h>

#define N_ROWS 16384
#define DIM 4096
#define NEXP 64
#define KWAVES 8
#define KSLICE (DIM / KWAVES)      // 512 k per wave
#define KC 32                      // k per chunk (one MFMA K-step)
#define NCHUNK (KSLICE / KC)       // 16
#define RPB 32                     // rows per block (2 M-tiles per wave)
#define NKO (DIM / 8)              // 512 k-octets

typedef short short8 __attribute__((ext_vector_type(8)));
typedef float f32x4  __attribute__((ext_vector_type(4)));

__device__ __forceinline__ unsigned cvt_pk_bf16(float a, float b) {
    unsigned r;
    asm("v_cvt_pk_bf16_f32 %0, %1, %2" : "=v"(r) : "v"(a), "v"(b));
    return r;   // low16 = bf16(a), high16 = bf16(b)
}

// 3-way split of 8 f32 into bf16 hi/mid/lo frags. Residual subtractions are
// exact, so x = h + m + l + eps with |eps| <= 2^-27 |x|.
__device__ __forceinline__ void split3(const float* xv, short8& h8, short8& m8, short8& l8) {
    union { unsigned u[4]; short8 s; } H, M, L;
#pragma unroll
    for (int j = 0; j < 4; ++j) {
        float a = xv[2 * j], b = xv[2 * j + 1];
        unsigned hp = cvt_pk_bf16(a, b);
        float a1 = a - __uint_as_float(hp << 16);
        float b1 = b - __uint_as_float(hp & 0xffff0000u);
        unsigned mp = cvt_pk_bf16(a1, b1);
        float a2 = a1 - __uint_as_float(mp << 16);
        float b2 = b1 - __uint_as_float(mp & 0xffff0000u);
        H.u[j] = hp; M.u[j] = mp; L.u[j] = cvt_pk_bf16(a2, b2);
    }
    h8 = H.s; m8 = M.s; l8 = L.s;
}

__device__ __forceinline__ bool gtpair(float a, int ia, float b, int ib) {
    return (a > b) || (a == b && ia < ib);
}

// ---- pre-kernel: W[64][4096] f32 -> three bf16 tables [ko][e] (k-octet packed) ----
__global__ __launch_bounds__(256)
void convw_kernel(const float* __restrict__ w, short8* __restrict__ w0t,
                  short8* __restrict__ w1t, short8* __restrict__ w2t)
{
    const int t  = blockIdx.x * 256 + threadIdx.x;   // 32768 = 512 ko x 64 e
    const int ko = t >> 6;
    const int e  = t & 63;
    const float* src = w + (size_t)e * DIM + ko * 8;
    float xv[8];
#pragma unroll
    for (int j = 0; j < 8; ++j) xv[j] = src[j];
    short8 h, m, l;
    split3(xv, h, m, l);
    w0t[ko * 64 + e] = h;
    w1t[ko * 64 + e] = m;
    w2t[ko * 64 + e] = l;
}

// ---- main: 512 blocks x 8 waves; wave wv covers k-slice wv*512..+512 for the
// block's 32 rows (2 M-tiles of 16). A-frag: row = lane&15, k-octet g = lane>>4
// (A/B share the k-order => any consistent order is valid). C-frag (m89):
// col = lane&15, row = (lane>>4)*4 + reg.
// FIFO discipline per body: [W(t) x12] then [x(t+2) x4] (newest). The first
// MFMA's W-wait force-drains x(t+1) at TWO bodies of flight (~600+ cyc >= HBM),
// and never touches the fresh x(t+2). 3-set rotating x registers (c/n/f).
__global__ __launch_bounds__(512, 4)
void gate_kernel(const float* __restrict__ x, const short8* __restrict__ w0t,
                 const short8* __restrict__ w1t, const short8* __restrict__ w2t,
                 float* __restrict__ out)
{
    __shared__ float part[KWAVES][RPB][NEXP];   // 64 KB

    const int tid  = threadIdx.x;
    const int lane = tid & 63;
    const int wv   = tid >> 6;                  // 0..7 = k-slice
    const int l15  = lane & 15;
    const int g    = lane >> 4;
    const int row0 = blockIdx.x * RPB;

    f32x4 acc[2][4];
#pragma unroll
    for (int mt = 0; mt < 2; ++mt)
#pragma unroll
        for (int nt = 0; nt < 4; ++nt) acc[mt][nt] = (f32x4){0.f, 0.f, 0.f, 0.f};

    const float* xp0 = x + (size_t)(row0 + l15) * DIM + wv * KSLICE + g * 8;
    const float* xp1 = xp0 + 16 * DIM;

#define LD4(P) (*reinterpret_cast<const float4*>(P))

    // x pipeline registers: c = chunk t, n = t+1, f = t+2
    float4 c00 = LD4(xp0),      c01 = LD4(xp0 + 4);
    float4 c10 = LD4(xp1),      c11 = LD4(xp1 + 4);
    float4 n00 = LD4(xp0 + 32), n01 = LD4(xp0 + 36);
    float4 n10 = LD4(xp1 + 32), n11 = LD4(xp1 + 36);
    float4 f00, f01, f10, f11;

#pragma unroll
    for (int t = 0; t < NCHUNK; ++t) {
        // --- 1) all 12 W loads for THIS chunk (enter FIFO before the fresh x) ---
        const int base = (wv * 64 + t * 4 + g) * 64 + l15;
        short8 b0[4], b1[4], b2[4];
#pragma unroll
        for (int nt = 0; nt < 4; ++nt) {
            b0[nt] = w0t[base + nt * 16];
            b1[nt] = w1t[base + nt * 16];
            b2[nt] = w2t[base + nt * 16];
        }
        // --- 2) x loads for chunk t+2 (newest in FIFO; drained 2 bodies later) ---
        const int tcf = (t + 2 < NCHUNK ? t + 2 : NCHUNK - 1) * KC;
        f00 = LD4(xp0 + tcf);      f01 = LD4(xp0 + tcf + 4);
        f10 = LD4(xp1 + tcf);      f11 = LD4(xp1 + tcf + 4);

        // --- 3) split current x (resident since last body's W-wait) ---
        float v0[8] = {c00.x, c00.y, c00.z, c00.w, c01.x, c01.y, c01.z, c01.w};
        float v1[8] = {c10.x, c10.y, c10.z, c10.w, c11.x, c11.y, c11.z, c11.w};
        short8 a0h, a0m, a0l, a1h, a1m, a1l;
        split3(v0, a0h, a0m, a0l);
        split3(v1, a1h, a1m, a1l);

        // --- 4) MFMAs (prio-boosted cluster) ---
        __builtin_amdgcn_s_setprio(1);
#pragma unroll
        for (int nt = 0; nt < 4; ++nt) {
            acc[0][nt] = __builtin_amdgcn_mfma_f32_16x16x32_bf16(a0l, b0[nt], acc[0][nt], 0, 0, 0);
            acc[0][nt] = __builtin_amdgcn_mfma_f32_16x16x32_bf16(a0m, b1[nt], acc[0][nt], 0, 0, 0);
            acc[0][nt] = __builtin_amdgcn_mfma_f32_16x16x32_bf16(a0h, b2[nt], acc[0][nt], 0, 0, 0);
            acc[0][nt] = __builtin_amdgcn_mfma_f32_16x16x32_bf16(a0m, b0[nt], acc[0][nt], 0, 0, 0);
            acc[0][nt] = __builtin_amdgcn_mfma_f32_16x16x32_bf16(a0h, b1[nt], acc[0][nt], 0, 0, 0);
            acc[0][nt] = __builtin_amdgcn_mfma_f32_16x16x32_bf16(a0h, b0[nt], acc[0][nt], 0, 0, 0);

            acc[1][nt] = __builtin_amdgcn_mfma_f32_16x16x32_bf16(a1l, b0[nt], acc[1][nt], 0, 0, 0);
            acc[1][nt] = __builtin_amdgcn_mfma_f32_16x16x32_bf16(a1m, b1[nt], acc[1][nt], 0, 0, 0);
            acc[1][nt] = __builtin_amdgcn_mfma_f32_16x16x32_bf16(a1h, b2[nt], acc[1][nt], 0, 0, 0);
            acc[1][nt] = __builtin_amdgcn_mfma_f32_16x16x32_bf16(a1m, b0[nt], acc[1][nt], 0, 0, 0);
            acc[1][nt] = __builtin_amdgcn_mfma_f32_16x16x32_bf16(a1h, b1[nt], acc[1][nt], 0, 0, 0);
            acc[1][nt] = __builtin_amdgcn_mfma_f32_16x16x32_bf16(a1h, b0[nt], acc[1][nt], 0, 0, 0);
        }
        __builtin_amdgcn_s_setprio(0);

        // --- 5) rotate x pipeline (renamed away by the unroll) ---
        c00 = n00; c01 = n01; c10 = n10; c11 = n11;
        n00 = f00; n01 = f01; n10 = f10; n11 = f11;
    }

    // ---- split-K partials to LDS (column XOR-swizzled by g => conflict-free) ----
#pragma unroll
    for (int mt = 0; mt < 2; ++mt)
#pragma unroll
        for (int nt = 0; nt < 4; ++nt)
#pragma unroll
            for (int r = 0; r < 4; ++r) {
                const int rw = mt * 16 + g * 4 + r;
                const int cl = (nt * 16 + l15) ^ (((rw >> 2) & 3) << 4);
                part[wv][rw][cl] = acc[mt][nt][r];
            }
    __syncthreads();

    float* out_vals = out;                          // [N][2]
    float* out_idx  = out + (size_t)N_ROWS * 2;     // [N][2] (as float)
    float* out_sc   = out + (size_t)N_ROWS * 4;     // [N][64]

    // wave wv finalizes rows wv*4 .. wv*4+3; lane = expert
#pragma unroll
    for (int i = 0; i < 4; ++i) {
        const int r = wv * 4 + i;
        const int row = row0 + r;
        const int cl = lane ^ (((r >> 2) & 3) << 4);
        float s = 0.f;
#pragma unroll
        for (int kw = 0; kw < KWAVES; ++kw) s += part[kw][r][cl];
        float m = s;
#pragma unroll
        for (int off = 32; off; off >>= 1) m = fmaxf(m, __shfl_xor(m, off));
        float e = expf(s - m);
        float sum = e;
#pragma unroll
        for (int off = 32; off; off >>= 1) sum += __shfl_xor(sum, off);
        float p = e / sum;
        out_sc[(size_t)row * 64 + lane] = p;

        // top-2 butterfly over 64 lanes (tie -> lowest index, matches lax.top_k)
        float v1 = p; int i1 = lane; float v2 = -1.f; int i2 = lane;
#pragma unroll
        for (int off = 32; off; off >>= 1) {
            float o1 = __shfl_xor(v1, off); int oi1 = __shfl_xor(i1, off);
            float o2 = __shfl_xor(v2, off); int oi2 = __shfl_xor(i2, off);
            if (gtpair(o1, oi1, v1, i1)) {
                if (gtpair(v1, i1, o2, oi2)) { v2 = v1; i2 = i1; }
                else                         { v2 = o2; i2 = oi2; }
                v1 = o1; i1 = oi1;
            } else if (gtpair(o1, oi1, v2, i2)) {
                v2 = o1; i2 = oi1;
            }
        }
        if (lane == 0) {
            out_vals[(size_t)row * 2 + 0] = v1;     // ROUTE_SCALE == 1.0
            out_vals[(size_t)row * 2 + 1] = v2;
            out_idx[(size_t)row * 2 + 0]  = (float)i1;
            out_idx[(size_t)row * 2 + 1]  = (float)i2;
        }
    }
}

extern "C" void kernel_launch(void* const* d_in, const int* in_sizes, int n_in,
                              void* d_out, int out_size, void* d_ws, size_t ws_size,
                              hipStream_t stream)
{
    const float* x = (const float*)d_in[0];
    const float* w = (const float*)d_in[1];
    float* out = (float*)d_out;

    short8* w0t = (short8*)d_ws;            // 512 KB
    short8* w1t = w0t + NKO * NEXP;         // 512 KB
    short8* w2t = w1t + NKO * NEXP;         // 512 KB

    convw_kernel<<<dim3(128), dim3(256), 0, stream>>>(w, w0t, w1t, w2t);
    gate_kernel<<<dim3(N_ROWS / RPB), dim3(512), 0, stream>>>(x, w0t, w1t, w2t, out);
}

// Round 15
// 120.932 us; speedup vs baseline: 1.6557x; 1.6557x over previous
//
#include <hip/hip_runtime.h>
#include <math.h>

#define N_ROWS 16384
#define DIM 4096
#define NEXP 64
#define RPB 32
#define NB 64                      // bodies; each ks-wave does 16 k per body

typedef short short8 __attribute__((ext_vector_type(8)));
typedef float f32x16 __attribute__((ext_vector_type(16)));

__device__ __forceinline__ unsigned cvt_pk_bf16(float a, float b) {
    unsigned r;
    asm("v_cvt_pk_bf16_f32 %0, %1, %2" : "=v"(r) : "v"(a), "v"(b));
    return r;   // low16 = bf16(a), high16 = bf16(b)
}

// 3-way split of 8 f32 into bf16 hi/mid/lo frags; residuals exact (<= 2^-27 |x|).
__device__ __forceinline__ void split3(const float* xv, short8& h8, short8& m8, short8& l8) {
    union { unsigned u[4]; short8 s; } H, M, L;
#pragma unroll
    for (int j = 0; j < 4; ++j) {
        float a = xv[2 * j], b = xv[2 * j + 1];
        unsigned hp = cvt_pk_bf16(a, b);
        float a1 = a - __uint_as_float(hp << 16);
        float b1 = b - __uint_as_float(hp & 0xffff0000u);
        unsigned mp = cvt_pk_bf16(a1, b1);
        float a2 = a1 - __uint_as_float(mp << 16);
        float b2 = b1 - __uint_as_float(mp & 0xffff0000u);
        H.u[j] = hp; M.u[j] = mp; L.u[j] = cvt_pk_bf16(a2, b2);
    }
    h8 = H.s; m8 = M.s; l8 = L.s;
}

__device__ __forceinline__ bool gtpair(float a, int ia, float b, int ib) {
    return (a > b) || (a == b && ia < ib);
}

// ---- pre-kernel: W -> ONE interleaved frag table.
// Unit U = 6*S + 2*tbl + eh (S = global 16-k step 0..255). Element U*64 + lane:
// expert e = eh*32 + (lane&31), k = S*16 + (lane>>5)*8  (32x32 B-frag mapping,
// r9/r13-verified). 16B units => gload_lds staging is unit-linear.
__global__ __launch_bounds__(256)
void convw_kernel(const float* __restrict__ w, short8* __restrict__ conv)
{
    const int t  = blockIdx.x * 256 + threadIdx.x;   // 32768 = 256 S x 2 eh x 64 l
    const int S  = t >> 7;
    const int eh = (t >> 6) & 1;
    const int l  = t & 63;
    const int e  = eh * 32 + (l & 31);
    const int k  = S * 16 + (l >> 5) * 8;
    const float* src = w + (size_t)e * DIM + k;
    float xv[8];
#pragma unroll
    for (int j = 0; j < 8; ++j) xv[j] = src[j];
    short8 h, m, lo;
    split3(xv, h, m, lo);
    conv[(size_t)(6 * S + 0 + eh) * 64 + l] = h;
    conv[(size_t)(6 * S + 2 + eh) * 64 + l] = m;
    conv[(size_t)(6 * S + 4 + eh) * 64 + l] = lo;
}

__device__ __forceinline__ void load16s(const short8* g, short8* l) {
    __builtin_amdgcn_global_load_lds(
        (const __attribute__((address_space(1))) void*)g,
        (__attribute__((address_space(3))) void*)l, 16, 0, 0);
}

#define MFMA32(A, B, C) __builtin_amdgcn_mfma_f32_32x32x16_bf16((A), (B), (C), 0, 0, 0)

// ---- main: 512 blocks x 8 waves = (ks 0..3, eh 0..1). Wave: 32 rows x 32
// experts (eh half) x k-quarter [ks*1024, +1024). Per body: 16 k. W staged
// block-wide into dbuf LDS via global_load_lds (24 KB/body, unit-linear, zero
// VGPR cost); per body: counted vmcnt(5) (drains body-t's 3 stage + 2 x loads,
// order-robust) + raw s_barrier pair. x: 3-set rotating register prefetch,
// 2 bodies deep. A: row = lane&31, k-octet = lane>>5 (matches conv k-order).
// C (m74/m101, r13-verified): col = lane&31, row = (reg&3)+8*(reg>>2)+4*(lane>>5).
__global__ __launch_bounds__(512, 4)
void gate_kernel(const float* __restrict__ x, const short8* __restrict__ conv,
                 float* __restrict__ out)
{
    __shared__ short8 stg[2][24][64];   // 48 KB: [buf][unit ks*6 + 2*tbl + eh][lane]

    const int tid  = threadIdx.x;
    const int lane = tid & 63;
    const int wv   = tid >> 6;          // 0..7
    const int eh   = wv & 1;
    const int ks   = wv >> 1;
    const int e31  = lane & 31;
    const int o    = lane >> 5;
    const int row0 = blockIdx.x * RPB;

    f32x16 acc;
#pragma unroll
    for (int j = 0; j < 16; ++j) acc[j] = 0.f;

    const float* xq = x + (size_t)(row0 + e31) * DIM + ks * 1024 + o * 8;

    // per-wave stage constants: units u = wv, wv+8, wv+16 (covers all 24)
    int cb[3], uu[3];
#pragma unroll
    for (int p = 0; p < 3; ++p) {
        const int u = p * 8 + wv;
        uu[p] = u;
        const int ksu = u / 6, fu = u % 6;
        cb[p] = 24576 * ksu + 64 * fu + lane;    // + 384*b per body (short8 units)
    }

#define STAGE(B, BF)                                                           \
    do {                                                                       \
        _Pragma("unroll")                                                      \
        for (int p_ = 0; p_ < 3; ++p_)                                         \
            load16s(conv + (size_t)cb[p_] + 384 * (B), &stg[BF][uu[p_]][0]);   \
    } while (0)

#define LD4(P) (*reinterpret_cast<const float4*>(P))

    // prologue: FIFO [S(0) x(0)] [S(1) x(1)]
    STAGE(0, 0);
    float4 c0 = LD4(xq),      c1 = LD4(xq + 4);
    STAGE(1, 1);
    float4 n0 = LD4(xq + 16), n1 = LD4(xq + 20);
    float4 f0, f1;

#pragma unroll 2
    for (int t = 0; t < NB; ++t) {
        const int buf = t & 1;
        // drain body t's group (3 stage + 2 x), keep body t+1's 5 in flight
        asm volatile("s_waitcnt vmcnt(5)" ::: "memory");
        __builtin_amdgcn_s_barrier();

        short8 b0 = stg[buf][ks * 6 + eh][lane];
        short8 b1 = stg[buf][ks * 6 + 2 + eh][lane];
        short8 b2 = stg[buf][ks * 6 + 4 + eh][lane];

        float xv[8] = {c0.x, c0.y, c0.z, c0.w, c1.x, c1.y, c1.z, c1.w};
        short8 ah, am, al;
        split3(xv, ah, am, al);

        acc = MFMA32(al, b0, acc);
        acc = MFMA32(am, b1, acc);
        acc = MFMA32(ah, b2, acc);
        acc = MFMA32(am, b0, acc);
        acc = MFMA32(ah, b1, acc);
        acc = MFMA32(ah, b0, acc);

        __builtin_amdgcn_s_barrier();   // all waves done reading buf
        const int tc = (t + 2 < NB) ? t + 2 : NB - 1;   // tail re-stage: harmless
        STAGE(tc, buf);
        f0 = LD4(xq + tc * 16);
        f1 = LD4(xq + tc * 16 + 4);
        c0 = n0; c1 = n1; n0 = f0; n1 = f1;
    }

    asm volatile("s_waitcnt vmcnt(0)" ::: "memory");
    __syncthreads();

    // ---- split-K combine: pf[ks][32 rows][64 experts] (reuse stage LDS) ----
    float* pf = (float*)&stg[0][0][0];
#pragma unroll
    for (int reg = 0; reg < 16; ++reg) {
        const int rw = (reg & 3) + 8 * (reg >> 2) + 4 * o;
        pf[(ks * 32 + rw) * 64 + eh * 32 + e31] = acc[reg];
    }
    __syncthreads();

    float* out_vals = out;                          // [N][2]
    float* out_idx  = out + (size_t)N_ROWS * 2;     // [N][2] (as float)
    float* out_sc   = out + (size_t)N_ROWS * 4;     // [N][64]

    // wave wv finalizes rows wv*4 .. wv*4+3; lane = expert
#pragma unroll
    for (int i = 0; i < 4; ++i) {
        const int r = wv * 4 + i;
        const int row = row0 + r;
        float s = pf[r * 64 + lane] + pf[(32 + r) * 64 + lane]
                + pf[(64 + r) * 64 + lane] + pf[(96 + r) * 64 + lane];
        float m = s;
#pragma unroll
        for (int off = 32; off; off >>= 1) m = fmaxf(m, __shfl_xor(m, off));
        float e = expf(s - m);
        float sum = e;
#pragma unroll
        for (int off = 32; off; off >>= 1) sum += __shfl_xor(sum, off);
        float p = e / sum;
        out_sc[(size_t)row * 64 + lane] = p;

        // top-2 butterfly over 64 lanes (tie -> lowest index, matches lax.top_k)
        float v1 = p; int i1 = lane; float v2 = -1.f; int i2 = lane;
#pragma unroll
        for (int off = 32; off; off >>= 1) {
            float o1 = __shfl_xor(v1, off); int oi1 = __shfl_xor(i1, off);
            float o2 = __shfl_xor(v2, off); int oi2 = __shfl_xor(i2, off);
            if (gtpair(o1, oi1, v1, i1)) {
                if (gtpair(v1, i1, o2, oi2)) { v2 = v1; i2 = i1; }
                else                         { v2 = o2; i2 = oi2; }
                v1 = o1; i1 = oi1;
            } else if (gtpair(o1, oi1, v2, i2)) {
                v2 = o1; i2 = oi1;
            }
        }
        if (lane == 0) {
            out_vals[(size_t)row * 2 + 0] = v1;     // ROUTE_SCALE == 1.0
            out_vals[(size_t)row * 2 + 1] = v2;
            out_idx[(size_t)row * 2 + 0]  = (float)i1;
            out_idx[(size_t)row * 2 + 1]  = (float)i2;
        }
    }
}

extern "C" void kernel_launch(void* const* d_in, const int* in_sizes, int n_in,
                              void* d_out, int out_size, void* d_ws, size_t ws_size,
                              hipStream_t stream)
{
    const float* x = (const float*)d_in[0];
    const float* w = (const float*)d_in[1];
    float* out = (float*)d_out;

    short8* conv = (short8*)d_ws;    // 1536 units x 64 lanes x 16 B = 1.5 MB

    convw_kernel<<<dim3(128), dim3(256), 0, stream>>>(w, conv);
    gate_kernel<<<dim3(N_ROWS / RPB), dim3(512), 0, stream>>>(x, conv, out);
}